// Round 11
// baseline (1283.308 us; speedup 1.0000x reference)
//
#include <hip/hip_runtime.h>
#include <hip/hip_bf16.h>
#include <stdint.h>

#define N_NODES 100000
#define DIM     64
#define NRELS   16
#define NBASE   8
#define HDIM    128
#define NEDGE   3200000
#define KDIM    1024               /* NRELS*DIM */

#define GRP     16                 /* nodes per bin = per fused block */
#define NBIN    (N_NODES / GRP)    /* 6250 exact */
#define CAP     768                /* bin capacity: mean 512 + 11 sigma */

#define PRO_VEFF_BLKS 512
#define PRO_VTXB_BLKS 12500        /* N*DIM/2/256 */
#define PRO_BLKS (PRO_VEFF_BLKS + PRO_VTXB_BLKS)

typedef __attribute__((ext_vector_type(8))) short  short8;
typedef __attribute__((ext_vector_type(4))) float  f32x4;

/* ---- ws layout (bytes) ---- */
#define OFF_VEFF  0u
#define OFF_VTXB  262144u                          /* N*DIM*2 = 12,800,000 */
#define OFF_BCUR  13062144u                        /* NBIN ints (pad)      */
#define OFF_REC1  13088768u                        /* NBIN*CAP*8           */
#define WS_NEED   (13088768u + (size_t)NBIN * CAP * 8u)

static __device__ __forceinline__ unsigned short f2bf(float x) {
    union { float f; unsigned u; } t; t.f = x;
    unsigned u = t.u;
    unsigned r = u + 0x7FFFu + ((u >> 16) & 1u);   /* RNE */
    return (unsigned short)(r >> 16);
}

/* ---- kernel 1: merged prologue (veff frag + vertex->bf16; verified r7-r10) ---- */
__global__ __launch_bounds__(256) void prologue(
        const float* __restrict__ W, const float* __restrict__ Wc,
        __hip_bfloat16* __restrict__ veff,
        const float* __restrict__ vert, unsigned* __restrict__ vb) {
    int b = blockIdx.x, t = threadIdx.x;
    if (b < PRO_VEFF_BLKS) {
        int idx = b * 256 + t;
        int c = idx >> 7;
        int h = idx & 127;
        float acc = 0.f;
#pragma unroll
        for (int bb = 0; bb < NBASE; ++bb)
            acc += Wc[(c & 15) * NBASE + bb] * W[(bb * DIM + (c >> 4)) * HDIM + h];
        int kt = c >> 5, ko = c & 31;
        int lane = ((ko >> 3) << 4) | (h & 15);
        int j = ko & 7;
        int hb = h >> 4;
        ((unsigned short*)veff)[(size_t)((kt * 8 + hb) * 64 + lane) * 8 + j] = f2bf(acc);
    } else {
        int i = (b - PRO_VEFF_BLKS) * 256 + t;     /* N*DIM/2 pairs exact */
        float2 f = ((const float2*)vert)[i];
        unsigned r;
        asm("v_cvt_pk_bf16_f32 %0, %1, %2" : "=v"(r) : "v"(f.x), "v"(f.y));
        vb[i] = r;
    }
}

/* ---- kernel 2: per-edge scatter into 16-node bins ----
   No ordering needed downstream (ds_add commutes) -> no LDS phases, no sort.
   Active write set = NBIN * 64B line = 400KB, L2-resident -> low inflation. ---- */
__global__ __launch_bounds__(256) void scatter1(
        const int* __restrict__ esrc, const int* __restrict__ edst,
        const int* __restrict__ erel, const float* __restrict__ eval,
        int* __restrict__ bcur, uint2* __restrict__ recs1) {
    int e = blockIdx.x * 256 + threadIdx.x;        /* grid exact: 3.2M */
    int dst = edst[e];
    int bin = dst >> 4;
    int pos = atomicAdd(&bcur[bin], 1);
    if (pos < CAP) {
        uint2 r;
        r.x = (unsigned)esrc[e] | ((unsigned)erel[e] << 17)
            | ((unsigned)(dst & 15) << 21);
        r.y = __float_as_uint(eval[e]);
        recs1[(size_t)bin * CAP + pos] = r;
    }
}

/* ---- kernel 3: fused ds_add_f32 aggregate + convert + MFMA GEMM ----
   512 thr / 8 waves / 16 nodes / 66.6KB LDS (2 blocks/CU).
   sup layout (f32, bank-randomized): dword = rowrel*65 + c*16 + p,
   rowrel = row*16+rel (8b from rec), element d = p*4+c.
   Quarter-wave per record: 16 lanes x 8B gather (= r7 pattern), 4 LDS
   atomic adds at constant offsets. No sort, no rel tracking, no __any. ---- */
__global__ __launch_bounds__(512, 4) void fused2(
        const unsigned short* __restrict__ vtxb, const uint2* __restrict__ recs1,
        const int* __restrict__ bcur, const __hip_bfloat16* __restrict__ veff,
        const float* __restrict__ bias, float* __restrict__ out) {
    __shared__ __align__(16) float sup[16640];     /* 256 rowrel * 65 dwords */
    int t = threadIdx.x;
    int g = blockIdx.x;
    int w = t >> 6, lane = t & 63;
    int q = lane >> 4, p = lane & 15;

    /* zero sup */
    for (int i = t; i < 16640 / 4; i += 512)
        *(f32x4*)&sup[i * 4] = (f32x4)0.f;
    __syncthreads();

    int cnt = bcur[g];
    if (cnt > CAP) cnt = CAP;
    const uint2* bw = recs1 + (size_t)g * CAP;
    const uint2* vtx2 = (const uint2*)vtxb;

    /* ---- aggregation: quarter-wave per record, exec-masked tail ---- */
    for (int idx = w * 4 + q; idx < cnt; idx += 32) {
        uint2 rec = bw[idx];
        unsigned rx = rec.x;
        float val = __uint_as_float(rec.y);
        uint2 vw = vtx2[(size_t)(rx & 0x1FFFFu) * 16 + p];
        unsigned rowrel = (rx >> 17) & 255u;
        unsigned di = rowrel * 65u + (unsigned)p;
        float f0 = __uint_as_float(vw.x << 16);
        float f1 = __uint_as_float(vw.x & 0xFFFF0000u);
        float f2 = __uint_as_float(vw.y << 16);
        float f3 = __uint_as_float(vw.y & 0xFFFF0000u);
        atomicAdd(&sup[di +  0], val * f0);
        atomicAdd(&sup[di + 16], val * f1);
        atomicAdd(&sup[di + 32], val * f2);
        atomicAdd(&sup[di + 48], val * f3);
    }
    __syncthreads();

    /* ---- convert: padded-c-major f32 -> XOR-swizzled bf16 A-tile ----
       Tile overlays sup bytes [0,32K); chunk c writes [c*8K,(c+1)*8K)
       and reads [c*16640,+16640): writes trail reads by a chunk -> safe
       with one barrier between read and write per chunk. ---- */
    {
        int lc = lane >> 4;            /* c 0..3  */
        int lp = lane & 15;            /* p 0..15 */
        int rowq = w & 3;
        int rh = w >> 2;               /* rel half */
        for (int ch = 0; ch < 4; ++ch) {
            int row = ch * 4 + rowq;
            float fv[8];
#pragma unroll
            for (int r = 0; r < 8; ++r)
                fv[r] = sup[(row * 16 + rh * 8 + r) * 65 + lc * 16 + lp];
            __syncthreads();
#pragma unroll
            for (int r = 0; r < 8; ++r) {
                unsigned pk;
                asm("v_cvt_pk_bf16_f32 %0, %1, %2" : "=v"(pk) : "v"(fv[r]), "v"(fv[r]));
                unsigned bc = (unsigned)((rh * 8 + r) * 128 + (lp * 4 + lc) * 2);
                unsigned addr = (unsigned)row * 2048u + (bc ^ ((unsigned)(row & 7) << 4));
                *(unsigned short*)((char*)sup + addr) = (unsigned short)pk;
            }
        }
    }
    __syncthreads();

    /* ---- GEMM: [16 x 1024] @ veff[1024 x 128]; wave w owns h-block w
       (r6-verified structure) ---- */
    int l15 = lane & 15, lhi = lane >> 4;
    unsigned axor = (unsigned)((l15 & 7) << 4);
    f32x4 acc0 = (f32x4)0.f;
#pragma unroll
    for (int kt = 0; kt < 32; ++kt) {
        short8 bf = ((const short8*)veff)[(size_t)(kt * 8 + w) * 64 + lane];
        unsigned cbo = (unsigned)(kt * 64 + lhi * 16);
        short8 a0 = *(const short8*)((char*)sup + (((unsigned)l15 * 2048u + cbo) ^ axor));
        acc0 = __builtin_amdgcn_mfma_f32_16x16x32_bf16(a0, bf, acc0, 0, 0, 0);
    }
    int h = w * 16 + l15;
    float bv = bias[h];
#pragma unroll
    for (int j = 0; j < 4; ++j)
        out[(size_t)(g * 16 + lhi * 4 + j) * HDIM + h] = acc0[j] + bv;
}

/* ---------- slow fallback (only if ws too small) ---------- */
__global__ __launch_bounds__(256) void build_veff_plain(
        const float* __restrict__ W, const float* __restrict__ Wc,
        float* __restrict__ veff) {
    int idx = blockIdx.x * 256 + threadIdx.x;
    int c = idx >> 7, h = idx & 127;
    float acc = 0.f;
#pragma unroll
    for (int b = 0; b < NBASE; ++b)
        acc += Wc[(c & 15) * NBASE + b] * W[(b * DIM + (c >> 4)) * HDIM + h];
    veff[c * HDIM + h] = acc;
}
__global__ __launch_bounds__(256) void init_out_bias(
        const float* __restrict__ bias, float* __restrict__ out) {
    int idx = blockIdx.x * 256 + threadIdx.x;
    if (idx < N_NODES * HDIM) out[idx] = bias[idx & 127];
}
__global__ __launch_bounds__(128) void edge_slow(
        const float* __restrict__ vertex, const float* __restrict__ eval,
        const int* __restrict__ esrc, const int* __restrict__ edst,
        const int* __restrict__ erel, const float* __restrict__ veff,
        float* __restrict__ out) {
    int e = blockIdx.x;
    int h = threadIdx.x;
    __shared__ float vrow[DIM];
    int src = esrc[e], dst = edst[e], rel = erel[e];
    float val = eval[e];
    if (h < DIM) vrow[h] = vertex[(size_t)src * DIM + h];
    __syncthreads();
    float acc = 0.f;
#pragma unroll 8
    for (int d = 0; d < DIM; ++d)
        acc += vrow[d] * veff[(rel * DIM + d) * HDIM + h];
    atomicAdd(out + (size_t)dst * HDIM + h, val * acc);
}

extern "C" void kernel_launch(void* const* d_in, const int* in_sizes, int n_in,
                              void* d_out, int out_size, void* d_ws, size_t ws_size,
                              hipStream_t stream) {
    const float* vertex   = (const float*)d_in[0];
    const float* edge_val = (const float*)d_in[1];
    const float* W        = (const float*)d_in[2];
    const float* W_comp   = (const float*)d_in[3];
    const float* B        = (const float*)d_in[4];
    const int*   edge_src = (const int*)d_in[5];
    const int*   edge_dst = (const int*)d_in[6];
    const int*   edge_rel = (const int*)d_in[7];
    float* out = (float*)d_out;

    if (ws_size >= WS_NEED) {
        __hip_bfloat16* veff = (__hip_bfloat16*)((char*)d_ws + OFF_VEFF);
        unsigned* vtxb = (unsigned*)((char*)d_ws + OFF_VTXB);
        int*   bcur  = (int*)((char*)d_ws + OFF_BCUR);
        uint2* recs1 = (uint2*)((char*)d_ws + OFF_REC1);

        hipMemsetAsync(bcur, 0, NBIN * sizeof(int), stream);
        prologue<<<PRO_BLKS, 256, 0, stream>>>(W, W_comp, veff, vertex, vtxb);
        scatter1<<<NEDGE / 256, 256, 0, stream>>>(
            edge_src, edge_dst, edge_rel, edge_val, bcur, recs1);
        fused2<<<NBIN, 512, 0, stream>>>(
            (const unsigned short*)vtxb, recs1, bcur, veff, B, out);
    } else {
        float* veff = (float*)d_ws;
        build_veff_plain<<<KDIM * HDIM / 256, 256, 0, stream>>>(W, W_comp, veff);
        init_out_bias<<<(N_NODES * HDIM + 255) / 256, 256, 0, stream>>>(B, out);
        edge_slow<<<NEDGE, 128, 0, stream>>>(
            vertex, edge_val, edge_src, edge_dst, edge_rel, veff, out);
    }
}

// Round 12
// 204.808 us; speedup vs baseline: 6.2659x; 6.2659x over previous
//
#include <hip/hip_runtime.h>
#include <hip/hip_bf16.h>
#include <stdint.h>

#define N_NODES 100000
#define DIM     64
#define NRELS   16
#define NBASE   8
#define HDIM    128
#define NEDGE   3200000
#define KDIM    1024               /* NRELS*DIM */

#define CBSH    7                  /* 128 nodes per coarse bucket */
#define CBN     128
#define NCB     782                /* ceil(100000/128) */
#define BCAP    4800               /* mean 4096 + 11 sigma */
#define SEGPB   (CBN * NRELS)      /* 2048 fine segments per bucket */
#define REC_PAD 256
#define NOFS_STRIDE 129            /* per-bucket node offsets + end sentinel */

#define P1_BLOCKS 500
#define P1_EPT    25               /* 500*256*25 = 3.2M exact (r7-verified) */

#define PRO_VEFF_BLKS 512
#define PRO_VTXB_BLKS 12500        /* N*DIM/2/256 */
#define TOT_BLKS (P1_BLOCKS + PRO_VEFF_BLKS + PRO_VTXB_BLKS)

typedef __attribute__((ext_vector_type(8))) short  short8;
typedef __attribute__((ext_vector_type(4))) float  f32x4;

/* ---- ws layout (bytes) ---- */
#define OFF_VEFF  0u
#define OFF_VTXB  262144u                          /* N*DIM*2 = 12,800,000 */
#define OFF_CUR   13062144u                        /* NCB ints (pad)       */
#define OFF_NOFS  13066240u                        /* NCB*129 ints (pad)   */
#define OFF_REC1  13473792u
#define REC_BYTES ((size_t)(NCB * BCAP + REC_PAD) * 8u)   /* 30,030,848 */
#define OFF_REC2  (13473792u + REC_BYTES)
#define WS_NEED   (OFF_REC2 + REC_BYTES)                  /* ~73.5 MB */

static __device__ __forceinline__ unsigned short f2bf(float x) {
    union { float f; unsigned u; } t; t.f = x;
    unsigned u = t.u;
    unsigned r = u + 0x7FFFu + ((u >> 16) & 1u);   /* RNE */
    return (unsigned short)(r >> 16);
}

/* ---- kernel 1: merged pass1 + prologue ----
   blocks [0,500): coarse scatter (r7-verified structure, 0-based cursors)
   blocks [500,1012): Veff B-frag build    blocks [1012,13512): vertex->bf16.
   pass1 blocks dispatch first -> prologue work overlaps pass1's tail. ---- */
__global__ __launch_bounds__(256) void pro_pass1(
        const int* __restrict__ esrc, const int* __restrict__ edst,
        const int* __restrict__ erel, const float* __restrict__ eval,
        int* __restrict__ cur, uint2* __restrict__ recs1,
        const float* __restrict__ W, const float* __restrict__ Wc,
        __hip_bfloat16* __restrict__ veff,
        const float* __restrict__ vert, unsigned* __restrict__ vb) {
    __shared__ int lcnt[NCB], lbase[NCB];
    int b = blockIdx.x, t = threadIdx.x;
    if (b < P1_BLOCKS) {
        int base = b * (256 * P1_EPT);
        for (int i = t; i < NCB; i += 256) lcnt[i] = 0;
        __syncthreads();
#pragma unroll 5
        for (int k = 0; k < P1_EPT; ++k)
            atomicAdd(&lcnt[edst[base + k * 256 + t] >> CBSH], 1);
        __syncthreads();
        for (int i = t; i < NCB; i += 256) {
            int c = lcnt[i];
            if (c > 0) lbase[i] = i * BCAP + atomicAdd(&cur[i], c);
            lcnt[i] = 0;                            /* reuse as local cursor */
        }
        __syncthreads();
#pragma unroll 5
        for (int k = 0; k < P1_EPT; ++k) {
            int e = base + k * 256 + t;
            int dst = edst[e];
            int cb = dst >> CBSH;
            int slot = atomicAdd(&lcnt[cb], 1);
            uint2 r;
            r.x = (unsigned)esrc[e] | ((unsigned)erel[e] << 17)
                | ((unsigned)(dst & (CBN - 1)) << 21);
            r.y = __float_as_uint(eval[e]);
            recs1[lbase[cb] + slot] = r;
        }
    } else if (b < P1_BLOCKS + PRO_VEFF_BLKS) {
        int idx = (b - P1_BLOCKS) * 256 + t;
        int c = idx >> 7;
        int h = idx & 127;
        float acc = 0.f;
#pragma unroll
        for (int bb = 0; bb < NBASE; ++bb)
            acc += Wc[(c & 15) * NBASE + bb] * W[(bb * DIM + (c >> 4)) * HDIM + h];
        int kt = c >> 5, ko = c & 31;
        int lane = ((ko >> 3) << 4) | (h & 15);
        int j = ko & 7;
        int hb = h >> 4;
        ((unsigned short*)veff)[(size_t)((kt * 8 + hb) * 64 + lane) * 8 + j] = f2bf(acc);
    } else {
        int i = (b - P1_BLOCKS - PRO_VEFF_BLKS) * 256 + t;  /* N*DIM/2 exact */
        float2 f = ((const float2*)vert)[i];
        unsigned r;
        asm("v_cvt_pk_bf16_f32 %0, %1, %2" : "=v"(r) : "v"(f.x), "v"(f.y));
        vb[i] = r;
    }
}

/* ---- kernel 2: fine scatter within L2-resident bucket window ----
   r7 structure at 128-node buckets: 782 blocks (2x parallelism, half-size
   serial windows). Thread t owns segments [t*8,(t+1)*8); node = t/2. ---- */
__global__ __launch_bounds__(256) void pass2_scatter(
        const uint2* __restrict__ recs1, const int* __restrict__ cur,
        int* __restrict__ nofs, uint2* __restrict__ recs2) {
    __shared__ int scur[SEGPB];
    __shared__ int wsum[4];
    int t = threadIdx.x;
    int cb = blockIdx.x;
    int r0 = cb * BCAP;
    int cnt = cur[cb]; if (cnt > BCAP) cnt = BCAP;
    int r1 = r0 + cnt;
    for (int i = t; i < SEGPB; i += 256) scur[i] = 0;
    __syncthreads();
    /* local fine histogram over 2048 segments */
    for (int i = r0 + t; i < r1; i += 256) {
        unsigned rx = recs1[i].x;
        int lseg = (int)(((rx >> 21) & 127u) * 16u + ((rx >> 17) & 15u));
        atomicAdd(&scur[lseg], 1);
    }
    __syncthreads();
    /* exclusive scan: thread t owns scur[t*8 .. t*8+7] */
    int b0 = t * 8;
    int vals[8]; int tsum = 0;
#pragma unroll
    for (int k = 0; k < 8; ++k) { vals[k] = scur[b0 + k]; tsum += vals[k]; }
    int lane = t & 63, w = t >> 6;
    int x = tsum;
#pragma unroll
    for (int d = 1; d < 64; d <<= 1) { int y = __shfl_up(x, d); if (lane >= d) x += y; }
    if (lane == 63) wsum[w] = x;
    __syncthreads();
    int wadd = 0;
    for (int i = 0; i < 4; ++i) if (i < w) wadd += wsum[i];
    int run = r0 + wadd + x - tsum;                 /* global exclusive base */
    if ((t & 1) == 0) nofs[cb * NOFS_STRIDE + (t >> 1)] = run;
#pragma unroll
    for (int k = 0; k < 8; ++k) { scur[b0 + k] = run; run += vals[k]; }
    if (t == 255) nofs[cb * NOFS_STRIDE + CBN] = run;   /* bucket end */
    __syncthreads();
    /* scatter within window (L2-resident) */
    for (int i = r0 + t; i < r1; i += 256) {
        uint2 r = recs1[i];
        int lseg = (int)(((r.x >> 21) & 127u) * 16u + ((r.x >> 17) & 15u));
        int pos = atomicAdd(&scur[lseg], 1);
        recs2[pos] = r;
    }
}

/* ---- kernel 3: fused branchless aggregate + MFMA GEMM ----
   EXACT r7-verified structure; deltas: nofs at 128-node buckets,
   32-bit gather index math (no size_t widen before the *16). ---- */
__global__ __launch_bounds__(512, 4) void fused_agg_gemm(
        const unsigned short* __restrict__ vtxb, const uint2* __restrict__ recs,
        const int* __restrict__ nofs, const __hip_bfloat16* __restrict__ veff,
        const float* __restrict__ bias, float* __restrict__ out) {
    __shared__ __align__(16) unsigned char smem[33 * 2048];   /* 32 A-rows + scratch */
    int t = threadIdx.x;
    int g = blockIdx.x;
    int w = t >> 6, lane = t & 63;
    int q = lane >> 4, p = lane & 15;
    int nloc = w * 4 + q;
    int n = g * 32 + nloc;

    for (int i = t; i < 33 * 2048 / 16; i += 512)
        ((uint4*)smem)[i] = make_uint4(0, 0, 0, 0);
    __syncthreads();

    int cbn = n >> CBSH, lo = n & (CBN - 1);
    int e0 = nofs[cbn * NOFS_STRIDE + lo];
    int e1 = nofs[cbn * NOFS_STRIDE + lo + 1];

    /* per-lane LDS write bases: addr = (active?rowb2:scrb2) + (rel<<7) */
    unsigned rowb2 = (unsigned)nloc * 2048u
                   + ((unsigned)(p * 8) ^ ((unsigned)(nloc & 7) << 4));
    unsigned scrb2 = 32u * 2048u + (unsigned)(p * 8);

    f32x4 acc = (f32x4)0.f;
    int currel = -1;
    const uint2* vtx2 = (const uint2*)vtxb;
    unsigned up = (unsigned)p;

    uint2 r0, r1, r2, r3, r4, r5, r6, r7;
    r0 = recs[e0 + 0]; r1 = recs[e0 + 1]; r2 = recs[e0 + 2]; r3 = recs[e0 + 3];
    r4 = recs[e0 + 4]; r5 = recs[e0 + 5]; r6 = recs[e0 + 6]; r7 = recs[e0 + 7];

    for (int base = e0; __any(base < e1); base += 8) {
        uint2 v0 = vtx2[(r0.x & 0x1FFFFu) * 16u + up];
        uint2 v1 = vtx2[(r1.x & 0x1FFFFu) * 16u + up];
        uint2 v2 = vtx2[(r2.x & 0x1FFFFu) * 16u + up];
        uint2 v3 = vtx2[(r3.x & 0x1FFFFu) * 16u + up];
        uint2 v4 = vtx2[(r4.x & 0x1FFFFu) * 16u + up];
        uint2 v5 = vtx2[(r5.x & 0x1FFFFu) * 16u + up];
        uint2 v6 = vtx2[(r6.x & 0x1FFFFu) * 16u + up];
        uint2 v7 = vtx2[(r7.x & 0x1FFFFu) * 16u + up];
        int nb = base + 8;
        uint2 n0 = recs[nb + 0], n1 = recs[nb + 1], n2 = recs[nb + 2], n3 = recs[nb + 3];
        uint2 n4 = recs[nb + 4], n5 = recs[nb + 5], n6 = recs[nb + 6], n7 = recs[nb + 7];

#define PROC(K, RK, VK)                                                       \
        {                                                                     \
            bool active = (base + (K)) < e1;                                  \
            int rel = (int)((RK.x >> 17) & 15u);                              \
            float val = active ? __uint_as_float(RK.y) : 0.f;                 \
            bool chg = (rel != currel) && active;                             \
            float f0 = __uint_as_float(VK.x << 16);                           \
            float f1 = __uint_as_float(VK.x & 0xFFFF0000u);                   \
            float f2 = __uint_as_float(VK.y << 16);                           \
            float f3 = __uint_as_float(VK.y & 0xFFFF0000u);                   \
            float t0 = chg ? 0.f : acc[0];                                    \
            float t1 = chg ? 0.f : acc[1];                                    \
            float t2 = chg ? 0.f : acc[2];                                    \
            float t3 = chg ? 0.f : acc[3];                                    \
            acc[0] = fmaf(val, f0, t0);                                       \
            acc[1] = fmaf(val, f1, t1);                                       \
            acc[2] = fmaf(val, f2, t2);                                       \
            acc[3] = fmaf(val, f3, t3);                                       \
            currel = active ? rel : currel;                                   \
            unsigned addr = (active ? rowb2 : scrb2) + ((unsigned)rel << 7);  \
            unsigned lo_, hi_;                                                \
            asm("v_cvt_pk_bf16_f32 %0, %1, %2" : "=v"(lo_)                    \
                : "v"(acc[0]), "v"(acc[1]));                                  \
            asm("v_cvt_pk_bf16_f32 %0, %1, %2" : "=v"(hi_)                    \
                : "v"(acc[2]), "v"(acc[3]));                                  \
            *(uint2*)(smem + addr) = make_uint2(lo_, hi_);                    \
        }
        PROC(0, r0, v0) PROC(1, r1, v1) PROC(2, r2, v2) PROC(3, r3, v3)
        PROC(4, r4, v4) PROC(5, r5, v5) PROC(6, r6, v6) PROC(7, r7, v7)
#undef PROC
        r0 = n0; r1 = n1; r2 = n2; r3 = n3;
        r4 = n4; r5 = n5; r6 = n6; r7 = n7;
    }
    __syncthreads();

    /* ---- GEMM: [32 x 1024] @ veff[1024 x 128]; wave w owns h-block w ---- */
    int l15 = lane & 15, lhi = lane >> 4;
    unsigned axor = (unsigned)((l15 & 7) << 4);
    f32x4 acc0 = (f32x4)0.f, acc1 = (f32x4)0.f;
#pragma unroll
    for (int kt = 0; kt < 32; ++kt) {
        short8 bf = ((const short8*)veff)[(size_t)(kt * 8 + w) * 64 + lane];
        unsigned cbo = (unsigned)(kt * 64 + lhi * 16);
        short8 a0 = *(const short8*)(smem + (((unsigned)l15 * 2048 + cbo) ^ axor));
        short8 a1 = *(const short8*)(smem + (((unsigned)(16 + l15) * 2048 + cbo) ^ axor));
        acc0 = __builtin_amdgcn_mfma_f32_16x16x32_bf16(a0, bf, acc0, 0, 0, 0);
        acc1 = __builtin_amdgcn_mfma_f32_16x16x32_bf16(a1, bf, acc1, 0, 0, 0);
    }
    int h = w * 16 + l15;
    float bv = bias[h];
#pragma unroll
    for (int j = 0; j < 4; ++j) {
        out[(size_t)(g * 32 + lhi * 4 + j) * HDIM + h]      = acc0[j] + bv;
        out[(size_t)(g * 32 + 16 + lhi * 4 + j) * HDIM + h] = acc1[j] + bv;
    }
}

/* ---------- slow fallback (only if ws too small) ---------- */
__global__ __launch_bounds__(256) void build_veff_plain(
        const float* __restrict__ W, const float* __restrict__ Wc,
        float* __restrict__ veff) {
    int idx = blockIdx.x * 256 + threadIdx.x;
    int c = idx >> 7, h = idx & 127;
    float acc = 0.f;
#pragma unroll
    for (int b = 0; b < NBASE; ++b)
        acc += Wc[(c & 15) * NBASE + b] * W[(b * DIM + (c >> 4)) * HDIM + h];
    veff[c * HDIM + h] = acc;
}
__global__ __launch_bounds__(256) void init_out_bias(
        const float* __restrict__ bias, float* __restrict__ out) {
    int idx = blockIdx.x * 256 + threadIdx.x;
    if (idx < N_NODES * HDIM) out[idx] = bias[idx & 127];
}
__global__ __launch_bounds__(128) void edge_slow(
        const float* __restrict__ vertex, const float* __restrict__ eval,
        const int* __restrict__ esrc, const int* __restrict__ edst,
        const int* __restrict__ erel, const float* __restrict__ veff,
        float* __restrict__ out) {
    int e = blockIdx.x;
    int h = threadIdx.x;
    __shared__ float vrow[DIM];
    int src = esrc[e], dst = edst[e], rel = erel[e];
    float val = eval[e];
    if (h < DIM) vrow[h] = vertex[(size_t)src * DIM + h];
    __syncthreads();
    float acc = 0.f;
#pragma unroll 8
    for (int d = 0; d < DIM; ++d)
        acc += vrow[d] * veff[(rel * DIM + d) * HDIM + h];
    atomicAdd(out + (size_t)dst * HDIM + h, val * acc);
}

extern "C" void kernel_launch(void* const* d_in, const int* in_sizes, int n_in,
                              void* d_out, int out_size, void* d_ws, size_t ws_size,
                              hipStream_t stream) {
    const float* vertex   = (const float*)d_in[0];
    const float* edge_val = (const float*)d_in[1];
    const float* W        = (const float*)d_in[2];
    const float* W_comp   = (const float*)d_in[3];
    const float* B        = (const float*)d_in[4];
    const int*   edge_src = (const int*)d_in[5];
    const int*   edge_dst = (const int*)d_in[6];
    const int*   edge_rel = (const int*)d_in[7];
    float* out = (float*)d_out;

    if (ws_size >= WS_NEED) {
        __hip_bfloat16* veff = (__hip_bfloat16*)((char*)d_ws + OFF_VEFF);
        unsigned* vtxb = (unsigned*)((char*)d_ws + OFF_VTXB);
        int*   cur   = (int*)((char*)d_ws + OFF_CUR);
        int*   nofs  = (int*)((char*)d_ws + OFF_NOFS);
        uint2* recs1 = (uint2*)((char*)d_ws + OFF_REC1);
        uint2* recs2 = (uint2*)((char*)d_ws + OFF_REC2);

        hipMemsetAsync(cur, 0, NCB * sizeof(int), stream);
        pro_pass1<<<TOT_BLKS, 256, 0, stream>>>(
            edge_src, edge_dst, edge_rel, edge_val, cur, recs1,
            W, W_comp, veff, vertex, vtxb);
        pass2_scatter<<<NCB, 256, 0, stream>>>(recs1, cur, nofs, recs2);
        fused_agg_gemm<<<N_NODES / 32, 512, 0, stream>>>(
            (const unsigned short*)vtxb, recs2, nofs, veff, B, out);
    } else {
        float* veff = (float*)d_ws;
        build_veff_plain<<<KDIM * HDIM / 256, 256, 0, stream>>>(W, W_comp, veff);
        init_out_bias<<<(N_NODES * HDIM + 255) / 256, 256, 0, stream>>>(B, out);
        edge_slow<<<NEDGE, 128, 0, stream>>>(
            vertex, edge_val, edge_src, edge_dst, edge_rel, veff, out);
    }
}

// Round 13
// 204.561 us; speedup vs baseline: 6.2735x; 1.0012x over previous
//
#include <hip/hip_runtime.h>
#include <hip/hip_bf16.h>
#include <stdint.h>

#define N_NODES 100000
#define DIM     64
#define NRELS   16
#define NBASE   8
#define HDIM    128
#define NEDGE   3200000
#define KDIM    1024               /* NRELS*DIM */

#define CBSH    8                  /* 256 nodes per coarse bucket (r7) */
#define CBN     256
#define NCB     391                /* ceil(100000/256) */
#define BCAP    9216               /* bucket capacity (verified r6-r12) */
#define SEGPB   (CBN * NRELS)      /* 4096 fine segments per bucket */
#define REC_PAD 256
#define NOFS_STRIDE 257            /* per-bucket node offsets + end sentinel */

#define P1_BLOCKS 500
#define P1_EPT    25               /* 500*256*25 = 3.2M exact (r7-verified) */

#define PRO_VEFF_BLKS 512
#define PRO_VTXB_BLKS 12500        /* N*DIM/2/256 */
#define PRO_BLKS (PRO_VEFF_BLKS + PRO_VTXB_BLKS + 2)

#define CAPB    1696               /* LDS record buffer (entries); 64 zero-pad */

typedef __attribute__((ext_vector_type(8))) short  short8;
typedef __attribute__((ext_vector_type(4))) float  f32x4;
typedef __attribute__((ext_vector_type(2))) unsigned u32x2;

/* ---- ws layout (bytes) ---- */
#define OFF_VEFF  0u
#define OFF_VTXB  262144u                          /* N*DIM*2 = 12,800,000 */
#define OFF_BCUR  13062144u                        /* NCB ints (pad)       */
#define OFF_NOFS  13064192u                        /* NCB*257 ints (pad)   */
#define OFF_REC1  13473792u
#define REC_BYTES ((size_t)(NCB * BCAP + REC_PAD) * 8u)
#define OFF_REC2  (13473792u + REC_BYTES)
#define WS_NEED   (OFF_REC2 + REC_BYTES)

static __device__ __forceinline__ unsigned short f2bf(float x) {
    union { float f; unsigned u; } t; t.f = x;
    unsigned u = t.u;
    unsigned r = u + 0x7FFFu + ((u >> 16) & 1u);   /* RNE */
    return (unsigned short)(r >> 16);
}

/* ---- kernel 1: merged prologue (verified r7-r10) ---- */
__global__ __launch_bounds__(256) void prologue(
        const float* __restrict__ W, const float* __restrict__ Wc,
        __hip_bfloat16* __restrict__ veff,
        const float* __restrict__ vert, unsigned* __restrict__ vb,
        int* __restrict__ bcur) {
    int b = blockIdx.x, t = threadIdx.x;
    if (b < PRO_VEFF_BLKS) {
        int idx = b * 256 + t;
        int c = idx >> 7;
        int h = idx & 127;
        float acc = 0.f;
#pragma unroll
        for (int bb = 0; bb < NBASE; ++bb)
            acc += Wc[(c & 15) * NBASE + bb] * W[(bb * DIM + (c >> 4)) * HDIM + h];
        int kt = c >> 5, ko = c & 31;
        int lane = ((ko >> 3) << 4) | (h & 15);
        int j = ko & 7;
        int hb = h >> 4;
        ((unsigned short*)veff)[(size_t)((kt * 8 + hb) * 64 + lane) * 8 + j] = f2bf(acc);
    } else if (b < PRO_VEFF_BLKS + PRO_VTXB_BLKS) {
        int i = (b - PRO_VEFF_BLKS) * 256 + t;     /* N*DIM/2 pairs exact */
        float2 f = ((const float2*)vert)[i];
        unsigned r;
        asm("v_cvt_pk_bf16_f32 %0, %1, %2" : "=v"(r) : "v"(f.x), "v"(f.y));
        vb[i] = r;
    } else {
        int i = (b - PRO_VEFF_BLKS - PRO_VTXB_BLKS) * 256 + t;
        if (i < NCB) bcur[i] = i * BCAP;
    }
}

/* ---- kernel 2: coarse scatter into fixed-capacity buckets (r7-verified) ---- */
__global__ __launch_bounds__(256) void pass1_scatter(
        const int* __restrict__ esrc, const int* __restrict__ edst,
        const int* __restrict__ erel, const float* __restrict__ eval,
        int* __restrict__ bcur, uint2* __restrict__ recs1) {
    __shared__ int lcnt[NCB], lbase[NCB];
    int t = threadIdx.x;
    int base = blockIdx.x * (256 * P1_EPT);
    for (int i = t; i < NCB; i += 256) lcnt[i] = 0;
    __syncthreads();
#pragma unroll 5
    for (int k = 0; k < P1_EPT; ++k)
        atomicAdd(&lcnt[edst[base + k * 256 + t] >> CBSH], 1);
    __syncthreads();
    for (int i = t; i < NCB; i += 256) {
        int c = lcnt[i];
        if (c > 0) lbase[i] = atomicAdd(&bcur[i], c);
        lcnt[i] = 0;
    }
    __syncthreads();
#pragma unroll 5
    for (int k = 0; k < P1_EPT; ++k) {
        int e = base + k * 256 + t;
        int dst = edst[e];
        int cb = dst >> CBSH;
        int slot = atomicAdd(&lcnt[cb], 1);
        uint2 r;
        r.x = (unsigned)esrc[e] | ((unsigned)erel[e] << 17)
            | ((unsigned)(dst & (CBN - 1)) << 21);
        r.y = __float_as_uint(eval[e]);
        recs1[lbase[cb] + slot] = r;
    }
}

/* ---- kernel 3: fine scatter within L2-resident bucket window (r7-verified) ---- */
__global__ __launch_bounds__(256) void pass2_scatter(
        const uint2* __restrict__ recs1, const int* __restrict__ bcur,
        int* __restrict__ nofs, uint2* __restrict__ recs2) {
    __shared__ int cur[SEGPB];
    __shared__ int wsum[4];
    int t = threadIdx.x;
    int cb = blockIdx.x;
    int r0 = cb * BCAP;
    int r1 = bcur[cb];
    int rend = r0 + BCAP; if (r1 > rend) r1 = rend;
    for (int i = t; i < SEGPB; i += 256) cur[i] = 0;
    __syncthreads();
    for (int i = r0 + t; i < r1; i += 256) {
        unsigned rx = recs1[i].x;
        int lseg = (int)(((rx >> 21) & 255u) * 16u + ((rx >> 17) & 15u));
        atomicAdd(&cur[lseg], 1);
    }
    __syncthreads();
    int b0 = t * 16;
    int vals[16]; int tsum = 0;
#pragma unroll
    for (int k = 0; k < 16; ++k) { vals[k] = cur[b0 + k]; tsum += vals[k]; }
    int lane = t & 63, w = t >> 6;
    int x = tsum;
#pragma unroll
    for (int d = 1; d < 64; d <<= 1) { int y = __shfl_up(x, d); if (lane >= d) x += y; }
    if (lane == 63) wsum[w] = x;
    __syncthreads();
    int wadd = 0;
    for (int i = 0; i < w; ++i) wadd += wsum[i];
    int run = r0 + wadd + x - tsum;
    nofs[cb * NOFS_STRIDE + t] = run;
#pragma unroll
    for (int k = 0; k < 16; ++k) { cur[b0 + k] = run; run += vals[k]; }
    if (t == 255) nofs[cb * NOFS_STRIDE + 256] = run;
    __syncthreads();
    for (int i = r0 + t; i < r1; i += 256) {
        uint2 r = recs1[i];
        int lseg = (int)(((r.x >> 21) & 255u) * 16u + ((r.x >> 17) & 15u));
        int pos = atomicAdd(&cur[lseg], 1);
        recs2[pos] = r;
    }
}

/* ---- kernel 4: fused aggregate + MFMA GEMM ----
   r7 PROC math, but: (a) block's records staged once into LDS (no global
   rec loads in the loop), (b) gathers issued via volatile inline asm with
   counted s_waitcnt vmcnt(16) (T4): depth-2 pipeline, 3 fixed register
   sets, unroll-3 (no rotation of in-flight registers). ---- */
__global__ __launch_bounds__(512, 4) void fused_agg_gemm(
        const unsigned short* __restrict__ vtxb, const u32x2* __restrict__ recs,
        const int* __restrict__ nofs, const __hip_bfloat16* __restrict__ veff,
        const float* __restrict__ bias, float* __restrict__ out) {
    __shared__ __align__(16) unsigned char smem[67584 + CAPB * 8];  /* 81152 B */
    u32x2* lrec = (u32x2*)(smem + 67584);
    int t = threadIdx.x;
    int g = blockIdx.x;
    int w = t >> 6, lane = t & 63;
    int q = lane >> 4, p = lane & 15;
    int nloc = w * 4 + q;

    /* zero A-tile + scratch row */
    for (int i = t; i < 67584 / 16; i += 512)
        ((uint4*)smem)[i] = make_uint4(0, 0, 0, 0);

    /* stage block's records into LDS (coalesced) + 64-entry zero pad */
    int cb_ = g >> 3;
    int lo0 = (g & 7) * 32;
    int start = nofs[cb_ * NOFS_STRIDE + lo0];
    int cnt = nofs[cb_ * NOFS_STRIDE + lo0 + 32] - start;
    if (cnt > CAPB - 64) cnt = CAPB - 64;
    for (int i = t; i < cnt; i += 512) lrec[i] = recs[start + i];
    if (t < 64) lrec[cnt + t] = (u32x2)(0u);
    __syncthreads();

    int le0q = nofs[cb_ * NOFS_STRIDE + lo0 + nloc] - start;
    int le1q = nofs[cb_ * NOFS_STRIDE + lo0 + nloc + 1] - start;
    if (le0q > cnt) le0q = cnt;
    if (le1q > cnt) le1q = cnt;
    int rem = le1q - le0q;

    unsigned rowb2 = (unsigned)nloc * 2048u
                   + ((unsigned)(p * 8) ^ ((unsigned)(nloc & 7) << 4));
    unsigned scrb2 = 32u * 2048u + (unsigned)(p * 8);

    f32x4 acc = (f32x4)0.f;
    int currel = -1;
    const u32x2* vtx2 = (const u32x2*)vtxb;
    unsigned up = (unsigned)p;

    u32x2 R0[8], R1[8], R2[8];      /* record chunks (from LDS) */
    u32x2 G0[8], G1[8], G2[8];      /* gather sets (asm in-flight) */

#define LDREC(RP, OFF)                                                        \
    {                                                                         \
        _Pragma("unroll")                                                     \
        for (int k = 0; k < 8; ++k) RP[k] = lrec[le0q + (OFF) + k];           \
    }
#define GISSUE(GI, RI)                                                        \
    {                                                                         \
        _Pragma("unroll")                                                     \
        for (int k = 0; k < 8; ++k) {                                         \
            const u32x2* ap = vtx2 + ((RI[k][0] & 0x1FFFFu) * 16u + up);      \
            asm volatile("global_load_dwordx2 %0, %1, off"                    \
                         : "=v"(GI[k]) : "v"(ap) : "memory");                 \
        }                                                                     \
    }
#define VWAIT16                                                               \
    asm volatile("s_waitcnt vmcnt(16)" ::: "memory");                         \
    __builtin_amdgcn_sched_barrier(0);
#define PROC1(K, RP, GP, OFF)                                                 \
    {                                                                         \
        bool active = ((OFF) + (K)) < rem;                                    \
        u32x2 RK = RP[K];                                                     \
        u32x2 VK = GP[K];                                                     \
        int rel = (int)((RK[0] >> 17) & 15u);                                 \
        float val = active ? __uint_as_float(RK[1]) : 0.f;                    \
        bool chg = (rel != currel) && active;                                 \
        float f0 = __uint_as_float(VK[0] << 16);                              \
        float f1 = __uint_as_float(VK[0] & 0xFFFF0000u);                      \
        float f2 = __uint_as_float(VK[1] << 16);                              \
        float f3 = __uint_as_float(VK[1] & 0xFFFF0000u);                      \
        float t0 = chg ? 0.f : acc[0];                                        \
        float t1 = chg ? 0.f : acc[1];                                        \
        float t2 = chg ? 0.f : acc[2];                                        \
        float t3 = chg ? 0.f : acc[3];                                        \
        acc[0] = fmaf(val, f0, t0);                                           \
        acc[1] = fmaf(val, f1, t1);                                           \
        acc[2] = fmaf(val, f2, t2);                                           \
        acc[3] = fmaf(val, f3, t3);                                           \
        currel = active ? rel : currel;                                       \
        unsigned addr = (active ? rowb2 : scrb2) + ((unsigned)rel << 7);      \
        unsigned lo_, hi_;                                                    \
        asm("v_cvt_pk_bf16_f32 %0, %1, %2" : "=v"(lo_)                        \
            : "v"(acc[0]), "v"(acc[1]));                                      \
        asm("v_cvt_pk_bf16_f32 %0, %1, %2" : "=v"(hi_)                        \
            : "v"(acc[2]), "v"(acc[3]));                                      \
        *(uint2*)(smem + addr) = make_uint2(lo_, hi_);                        \
    }
#define PROC8(GP, RP, OFF)                                                    \
    PROC1(0, RP, GP, OFF) PROC1(1, RP, GP, OFF) PROC1(2, RP, GP, OFF)         \
    PROC1(3, RP, GP, OFF) PROC1(4, RP, GP, OFF) PROC1(5, RP, GP, OFF)         \
    PROC1(6, RP, GP, OFF) PROC1(7, RP, GP, OFF)
#define ITER(GP, RP, GI, RI, OFF)                                             \
    GISSUE(GI, RI)                                                            \
    VWAIT16                                                                   \
    PROC8(GP, RP, OFF)                                                        \
    LDREC(RP, (OFF) + 24)

    /* pipeline prologue: recs chunks 0-2 from LDS; gathers chunk 0,1 issued */
    LDREC(R0, 0) LDREC(R1, 8) LDREC(R2, 16)
    GISSUE(G0, R0) GISSUE(G1, R1)

    for (int off = 0; __any(off < rem); off += 24) {
        ITER(G0, R0, G2, R2, off)
        ITER(G1, R1, G0, R0, off + 8)
        ITER(G2, R2, G1, R1, off + 16)
    }
#undef ITER
#undef PROC8
#undef PROC1
#undef VWAIT16
#undef GISSUE
#undef LDREC
    __syncthreads();

    /* ---- GEMM: [32 x 1024] @ veff[1024 x 128]; wave w owns h-block w ---- */
    int l15 = lane & 15, lhi = lane >> 4;
    unsigned axor = (unsigned)((l15 & 7) << 4);
    f32x4 acc0 = (f32x4)0.f, acc1 = (f32x4)0.f;
#pragma unroll
    for (int kt = 0; kt < 32; ++kt) {
        short8 bf = ((const short8*)veff)[(size_t)(kt * 8 + w) * 64 + lane];
        unsigned cbo = (unsigned)(kt * 64 + lhi * 16);
        short8 a0 = *(const short8*)(smem + (((unsigned)l15 * 2048 + cbo) ^ axor));
        short8 a1 = *(const short8*)(smem + (((unsigned)(16 + l15) * 2048 + cbo) ^ axor));
        acc0 = __builtin_amdgcn_mfma_f32_16x16x32_bf16(a0, bf, acc0, 0, 0, 0);
        acc1 = __builtin_amdgcn_mfma_f32_16x16x32_bf16(a1, bf, acc1, 0, 0, 0);
    }
    int h = w * 16 + l15;
    float bv = bias[h];
#pragma unroll
    for (int j = 0; j < 4; ++j) {
        out[(size_t)(g * 32 + lhi * 4 + j) * HDIM + h]      = acc0[j] + bv;
        out[(size_t)(g * 32 + 16 + lhi * 4 + j) * HDIM + h] = acc1[j] + bv;
    }
}

/* ---------- slow fallback (only if ws too small) ---------- */
__global__ __launch_bounds__(256) void build_veff_plain(
        const float* __restrict__ W, const float* __restrict__ Wc,
        float* __restrict__ veff) {
    int idx = blockIdx.x * 256 + threadIdx.x;
    int c = idx >> 7, h = idx & 127;
    float acc = 0.f;
#pragma unroll
    for (int b = 0; b < NBASE; ++b)
        acc += Wc[(c & 15) * NBASE + b] * W[(b * DIM + (c >> 4)) * HDIM + h];
    veff[c * HDIM + h] = acc;
}
__global__ __launch_bounds__(256) void init_out_bias(
        const float* __restrict__ bias, float* __restrict__ out) {
    int idx = blockIdx.x * 256 + threadIdx.x;
    if (idx < N_NODES * HDIM) out[idx] = bias[idx & 127];
}
__global__ __launch_bounds__(128) void edge_slow(
        const float* __restrict__ vertex, const float* __restrict__ eval,
        const int* __restrict__ esrc, const int* __restrict__ edst,
        const int* __restrict__ erel, const float* __restrict__ veff,
        float* __restrict__ out) {
    int e = blockIdx.x;
    int h = threadIdx.x;
    __shared__ float vrow[DIM];
    int src = esrc[e], dst = edst[e], rel = erel[e];
    float val = eval[e];
    if (h < DIM) vrow[h] = vertex[(size_t)src * DIM + h];
    __syncthreads();
    float acc = 0.f;
#pragma unroll 8
    for (int d = 0; d < DIM; ++d)
        acc += vrow[d] * veff[(rel * DIM + d) * HDIM + h];
    atomicAdd(out + (size_t)dst * HDIM + h, val * acc);
}

extern "C" void kernel_launch(void* const* d_in, const int* in_sizes, int n_in,
                              void* d_out, int out_size, void* d_ws, size_t ws_size,
                              hipStream_t stream) {
    const float* vertex   = (const float*)d_in[0];
    const float* edge_val = (const float*)d_in[1];
    const float* W        = (const float*)d_in[2];
    const float* W_comp   = (const float*)d_in[3];
    const float* B        = (const float*)d_in[4];
    const int*   edge_src = (const int*)d_in[5];
    const int*   edge_dst = (const int*)d_in[6];
    const int*   edge_rel = (const int*)d_in[7];
    float* out = (float*)d_out;

    if (ws_size >= WS_NEED) {
        __hip_bfloat16* veff = (__hip_bfloat16*)((char*)d_ws + OFF_VEFF);
        unsigned* vtxb = (unsigned*)((char*)d_ws + OFF_VTXB);
        int*   bcur  = (int*)((char*)d_ws + OFF_BCUR);
        int*   nofs  = (int*)((char*)d_ws + OFF_NOFS);
        uint2* recs1 = (uint2*)((char*)d_ws + OFF_REC1);
        uint2* recs2 = (uint2*)((char*)d_ws + OFF_REC2);

        prologue<<<PRO_BLKS, 256, 0, stream>>>(W, W_comp, veff, vertex, vtxb, bcur);
        pass1_scatter<<<P1_BLOCKS, 256, 0, stream>>>(
            edge_src, edge_dst, edge_rel, edge_val, bcur, recs1);
        pass2_scatter<<<NCB, 256, 0, stream>>>(recs1, bcur, nofs, recs2);
        fused_agg_gemm<<<N_NODES / 32, 512, 0, stream>>>(
            (const unsigned short*)vtxb, (const u32x2*)recs2, nofs, veff, B, out);
    } else {
        float* veff = (float*)d_ws;
        build_veff_plain<<<KDIM * HDIM / 256, 256, 0, stream>>>(W, W_comp, veff);
        init_out_bias<<<(N_NODES * HDIM + 255) / 256, 256, 0, stream>>>(B, out);
        edge_slow<<<NEDGE, 128, 0, stream>>>(
            vertex, edge_val, edge_src, edge_dst, edge_rel, veff, out);
    }
}